// Round 10
// baseline (44.079 us; speedup 1.0000x reference)
//
#include <hip/hip_runtime.h>
#include <math.h>

#define NB 64
#define NS 512
#define NH 768
#define NT 3
#define EMIS_N (NB * NS * NT)   // 98304
#define NEGINF (-1e30f)
#define PSTRIDE 16              // floats per block partial (9 mat, 1 np, 3 e0-vec)
#define BPB 32                  // blocks per batch (512 rows / 16)
#define NBLK 2048

__device__ __forceinline__ float lse3(float a, float b, float c) {
    float m = fmaxf(fmaxf(a, b), c);
    return m + __logf(__expf(a - m) + __expf(b - m) + __expf(c - m));
}

// Atomic-RMW read at the device coherent point (cross-XCD safe, stale-L2 safe).
__device__ __forceinline__ float aread(float* p) { return atomicAdd(p, 0.0f); }

// ---------------------------------------------------------------------------
// Single fused kernel + a 260-byte ticket-zeroing memset node before it.
// Per block (16 rows of one batch):
//   1. hoist scattered label/mask loads; GEMV (hidden float4 stream x W in L1).
//   2. per-wave CRF 3x3 log-semiring partial + numerator term.
//   3. fold 4 wave partials -> block partial; publish via atomicExch (RMW at
//      the device coherent point; no fences, no L2 writeback storms).
//   4. per-batch ticket (atomicAdd, zeroed each launch): the TRUE last arriver
//      (old == 31) re-reads the 32 partials via atomicAdd(p,0) RMW-reads,
//      ordered 32-leaf shfl tree -> per-batch nll (atomicExch).
//   5. final ticket: the 64th batch-winner (old == 63) sums -> out[EMIS_N].
// r8/r9 bug fixed: with poisoned tickets the (old&N-1)==N-1 test picked a
// NON-last arriver (V mod N != 0), which combined unpublished partials.
// Tickets are now memset to 0 on the stream before every kernel launch.
// ---------------------------------------------------------------------------
__global__ __launch_bounds__(256) void fused_emis_crf(
    const float* __restrict__ hidden,   // [NB*NS, NH]
    const int*   __restrict__ labels,   // [NB, NS]
    const int*   __restrict__ mask,     // [NB, NS]
    const float* __restrict__ W,        // [NH, NT]
    const float* __restrict__ bias,     // [NT]
    const float* __restrict__ trans,    // [NT, NT]
    const float* __restrict__ startv,   // [NT]
    const float* __restrict__ endv,     // [NT]
    float* __restrict__ out,            // emissions [NB*NS, NT], then nll
    float* __restrict__ partials,       // [NBLK][PSTRIDE]
    float* __restrict__ nslots,         // [NB] per-batch nll
    unsigned int* __restrict__ btick,   // [NB] per-batch tickets (zeroed)
    unsigned int* __restrict__ ftick)   // final ticket (zeroed)
{
    __shared__ float sP[4][12];
    __shared__ float sE[3];

    const int tid  = threadIdx.x;
    const int lane = tid & 63;
    const int wv   = tid >> 6;
    const int blk  = blockIdx.x;
    const int wid  = blk * 4 + wv;
    const int sub  = lane & 15;
    const int rsel = lane >> 4;
    const int row  = wid * 4 + rsel;
    const int b    = row >> 9;
    const int p    = row & (NS - 1);

    // ---- hoisted scattered loads (consumed in the tail) ----
    const int* lrow = labels + b * NS;
    const int* mrow = mask   + b * NS;
    int mk = 0, labc = 0, labp = 0;
    if (sub == 0) {
        mk   = mrow[p];
        labc = lrow[p];
        labp = lrow[p - (p > 0 ? 1 : 0)];
    }

    // ---- GEMV (r3 body): hidden float4 stream x W from L1 ----
    const float* hrow = hidden + (size_t)row * NH;
    float a0 = 0.f, a1 = 0.f, a2 = 0.f;
    #pragma unroll
    for (int it = 0; it < 12; ++it) {
        const int h0 = it * 64 + sub * 4;
        const float4 x  = *reinterpret_cast<const float4*>(hrow + h0);
        const float4 q0 = *reinterpret_cast<const float4*>(W + h0 * 3);
        const float4 q1 = *reinterpret_cast<const float4*>(W + h0 * 3 + 4);
        const float4 q2 = *reinterpret_cast<const float4*>(W + h0 * 3 + 8);
        a0 = fmaf(x.x, q0.x, a0); a1 = fmaf(x.x, q0.y, a1); a2 = fmaf(x.x, q0.z, a2);
        a0 = fmaf(x.y, q0.w, a0); a1 = fmaf(x.y, q1.x, a1); a2 = fmaf(x.y, q1.y, a2);
        a0 = fmaf(x.z, q1.z, a0); a1 = fmaf(x.z, q1.w, a1); a2 = fmaf(x.z, q2.x, a2);
        a0 = fmaf(x.w, q2.y, a0); a1 = fmaf(x.w, q2.z, a1); a2 = fmaf(x.w, q2.w, a2);
    }
    #pragma unroll
    for (int d = 8; d; d >>= 1) {
        a0 += __shfl_xor(a0, d);
        a1 += __shfl_xor(a1, d);
        a2 += __shfl_xor(a2, d);
    }

    const float e0 = fmaxf(a0 + bias[0], 0.f);
    const float e1 = fmaxf(a1 + bias[1], 0.f);
    const float e2 = fmaxf(a2 + bias[2], 0.f);

    if (sub < 3) out[row * NT + sub] = (sub == 0) ? e0 : (sub == 1) ? e1 : e2;

    // ---- numerator term ----
    float term = 0.f;
    if (sub == 0) {
        const float esel = (labc == 0) ? e0 : (labc == 1) ? e1 : e2;
        if (p == 0) {
            term = startv[labc] + esel;               // boundary term
        } else if (mk) {
            term = trans[labp * 3 + labc] + esel;     // step term
        }
    }

    // ---- compose the wave's 4 step matrices (9 active lanes) ----
    const int il = (lane < 9) ? (lane / 3) : 0;
    const int jl = (lane < 9) ? (lane % 3) : 0;
    const float tc0 = trans[jl], tc1 = trans[3 + jl], tc2 = trans[6 + jl];
    float Pv = (il == jl) ? 0.f : NEGINF;

    const int pbase = p & ~3;
    #pragma unroll
    for (int k = 0; k < 4; ++k) {
        const int src = k << 4;
        const float ee0 = __shfl(e0, src);
        const float ee1 = __shfl(e1, src);
        const float ee2 = __shfl(e2, src);
        const int   mm  = __shfl(mk, src);
        const float Pi0 = __shfl(Pv, il * 3 + 0);
        const float Pi1 = __shfl(Pv, il * 3 + 1);
        const float Pi2 = __shfl(Pv, il * 3 + 2);
        const float ej  = (jl == 0) ? ee0 : (jl == 1) ? ee1 : ee2;
        const float q   = lse3(Pi0 + tc0, Pi1 + tc1, Pi2 + tc2) + ej;
        const bool act  = ((pbase + k) >= 1) && (mm != 0);
        Pv = act ? q : Pv;
    }

    const float np = __shfl(term, 0) + __shfl(term, 16) +
                     __shfl(term, 32) + __shfl(term, 48);

    if (lane < 9)  sP[wv][lane] = Pv;
    if (lane == 0) sP[wv][9]    = np;
    if ((blk & (BPB - 1)) == 0 && wv == 0 && lane == 0) {
        sE[0] = e0; sE[1] = e1; sE[2] = e2;          // position-0 emissions
    }
    __syncthreads();
    if (wv != 0) return;

    // ---- fold 4 wave partials -> block partial (wave 0) ----
    float Pb = (lane < 9) ? sP[0][lane] : 0.f;
    #pragma unroll
    for (int k = 1; k < 4; ++k) {
        const float Pi0 = __shfl(Pb, il * 3 + 0);
        const float Pi1 = __shfl(Pb, il * 3 + 1);
        const float Pi2 = __shfl(Pb, il * 3 + 2);
        const float q = lse3(Pi0 + sP[k][jl],
                             Pi1 + sP[k][3 + jl],
                             Pi2 + sP[k][6 + jl]);
        Pb = (lane < 9) ? q : Pb;
    }
    const float npb = sP[0][9] + sP[1][9] + sP[2][9] + sP[3][9];

    // ---- publish block partial via atomicExch (RMW -> coherent point) ----
    float* wp = partials + (size_t)blk * PSTRIDE;
    if (lane < 9)  atomicExch(wp + lane, Pb);
    if (lane == 9) atomicExch(wp + 9, npb);
    if ((blk & (BPB - 1)) == 0 && lane >= 10 && lane < 13)
        atomicExch(wp + lane, sE[lane - 10]);
    asm volatile("s_waitcnt vmcnt(0)" ::: "memory");   // publishes complete

    // ---- per-batch ticket: TRUE last arriver (old == BPB-1) combines ----
    unsigned int old = 0u;
    if (lane == 0) old = atomicAdd(btick + b, 1u);
    old = (unsigned int)__shfl((int)old, 0);
    if (old != (BPB - 1u)) return;

    // ---- combine batch b: RMW-reads of the 32 partials ----
    float P[9] = {0.f, NEGINF, NEGINF, NEGINF, 0.f, NEGINF, NEGINF, NEGINF, 0.f};
    float np2 = 0.f;
    if (lane < BPB) {
        float* pa = partials + ((size_t)b * BPB + lane) * PSTRIDE;
        #pragma unroll
        for (int i = 0; i < 9; ++i) P[i] = aread(pa + i);
        np2 = aread(pa + 9);
    }

    int lsum = 0;
    #pragma unroll
    for (int k = 0; k < 8; ++k) lsum += mrow[lane + k * 64];
    #pragma unroll
    for (int d = 32; d; d >>= 1) lsum += __shfl_xor(lsum, d);
    const int len = lsum;

    #pragma unroll
    for (int d = 1; d < BPB; d <<= 1) {
        float Q[9];
        #pragma unroll
        for (int i = 0; i < 9; ++i) Q[i] = __shfl_down(P[i], d);
        const bool valid = (lane + d) < BPB;
        float R[9];
        #pragma unroll
        for (int i = 0; i < 3; ++i)
            #pragma unroll
            for (int j = 0; j < 3; ++j)
                R[i * 3 + j] = lse3(P[i * 3 + 0] + Q[0 + j],
                                    P[i * 3 + 1] + Q[3 + j],
                                    P[i * 3 + 2] + Q[6 + j]);
        #pragma unroll
        for (int i = 0; i < 9; ++i) P[i] = valid ? R[i] : P[i];
    }

    #pragma unroll
    for (int d = 32; d; d >>= 1) np2 += __shfl_xor(np2, d);

    if (lane == 0) {
        float* pa0 = partials + (size_t)b * BPB * PSTRIDE;
        const float ae0 = aread(pa0 + 10);
        const float ae1 = aread(pa0 + 11);
        const float ae2 = aread(pa0 + 12);
        const float b0 = startv[0] + ae0;
        const float b1 = startv[1] + ae1;
        const float b2 = startv[2] + ae2;
        const float f0 = lse3(b0 + P[0], b1 + P[3], b2 + P[6]);
        const float f1 = lse3(b0 + P[1], b1 + P[4], b2 + P[7]);
        const float f2 = lse3(b0 + P[2], b1 + P[5], b2 + P[8]);
        const float logZ = lse3(f0 + endv[0], f1 + endv[1], f2 + endv[2]);
        const int tl = lrow[len - 1];
        atomicExch(nslots + b, logZ - (np2 + endv[tl]));
    }
    asm volatile("s_waitcnt vmcnt(0)" ::: "memory");

    // ---- final ticket: the 64th batch-winner (old == NB-1) sums ----
    unsigned int o2 = 0u;
    if (lane == 0) o2 = atomicAdd(ftick, 1u);
    o2 = (unsigned int)__shfl((int)o2, 0);
    if (o2 != (NB - 1u)) return;

    float v = aread(nslots + lane);
    #pragma unroll
    for (int d = 32; d; d >>= 1) v += __shfl_xor(v, d);
    if (lane == 0) out[EMIS_N] = v;
}

extern "C" void kernel_launch(void* const* d_in, const int* in_sizes, int n_in,
                              void* d_out, int out_size, void* d_ws, size_t ws_size,
                              hipStream_t stream) {
    const float* hidden = (const float*)d_in[0];
    const int*   labels = (const int*)  d_in[1];
    const int*   maskp  = (const int*)  d_in[2];
    const float* W      = (const float*)d_in[3];
    const float* bias   = (const float*)d_in[4];
    const float* trans  = (const float*)d_in[5];
    const float* startv = (const float*)d_in[6];
    const float* endv   = (const float*)d_in[7];
    float* out = (float*)d_out;

    float*        partials = (float*)d_ws;                 // 2048*16*4 = 128 KB
    float*        nslots   = partials + NBLK * PSTRIDE;    // 64 floats
    unsigned int* btick    = (unsigned int*)(nslots + NB); // 64 uints
    unsigned int* ftick    = btick + NB;                   // 1 uint

    // Zero the tickets every launch (260 B) so "last arriver" is well-defined.
    hipMemsetAsync(btick, 0, (NB + 1) * sizeof(unsigned int), stream);

    fused_emis_crf<<<NBLK, 256, 0, stream>>>(hidden, labels, maskp, W, bias,
                                             trans, startv, endv, out,
                                             partials, nslots, btick, ftick);
}

// Round 11
// 28.223 us; speedup vs baseline: 1.5618x; 1.5618x over previous
//
#include <hip/hip_runtime.h>
#include <math.h>

#define NB 64
#define NS 512
#define NH 768
#define NT 3
#define EMIS_N (NB * NS * NT)   // 98304
#define NEGINF (-1e30f)
#define PSTRIDE 12              // floats per block partial in ws
#define BPB 16                  // blocks per batch (512 rows / 32)
#define NBLK 1024               // emis blocks (512 threads each)

__device__ __forceinline__ float lse3(float a, float b, float c) {
    float m = fmaxf(fmaxf(a, b), c);
    return m + __logf(__expf(a - m) + __expf(b - m) + __expf(c - m));
}

// ---------------------------------------------------------------------------
// Kernel 1: emissions = relu(hidden @ W + b) fused with per-BLOCK CRF partial.
// 1024 blocks x 512 threads (8 waves) = 4 blocks/CU, one full residency round.
// Per wave: 16 lanes/row, 4 rows; GEMV hidden float4 stream x W via L1;
// log-semiring 3x3 compose of the wave's 4 steps; 8 wave partials folded to
// one block partial in LDS by wave 0.
// ---------------------------------------------------------------------------
__global__ __launch_bounds__(512) void emis_crf_kernel(
    const float* __restrict__ hidden,   // [NB*NS, NH]
    const int*   __restrict__ labels,   // [NB, NS]
    const int*   __restrict__ mask,     // [NB, NS]
    const float* __restrict__ W,        // [NH, NT]
    const float* __restrict__ bias,     // [NT]
    const float* __restrict__ trans,    // [NT, NT]
    const float* __restrict__ startv,   // [NT]
    float* __restrict__ out,            // emissions [NB*NS, NT], then nll
    float* __restrict__ ws)             // [NBLK][PSTRIDE]
{
    __shared__ float sP[8][12];

    const int tid  = threadIdx.x;
    const int lane = tid & 63;
    const int wv   = tid >> 6;               // wave 0..7
    const int wid  = blockIdx.x * 8 + wv;    // 0..8191
    const int sub  = lane & 15;              // h-chunk within row
    const int rsel = lane >> 4;              // which of the wave's 4 rows
    const int row  = wid * 4 + rsel;
    const int b    = row >> 9;               // batch
    const int p    = row & (NS - 1);         // position in sequence

    if (blockIdx.x == 0 && tid == 0) out[EMIS_N] = 0.0f;   // init nll acc

    // ---- hoisted scattered loads (consumed in the tail) ----
    const int* lrow = labels + b * NS;
    const int* mrow = mask   + b * NS;
    int mk = 0, labc = 0, labp = 0;
    if (sub == 0) {
        mk   = mrow[p];
        labc = lrow[p];
        labp = lrow[p - (p > 0 ? 1 : 0)];
    }

    // ---- GEMV: hidden float4 stream x W from L1 ----
    const float* hrow = hidden + (size_t)row * NH;
    float a0 = 0.f, a1 = 0.f, a2 = 0.f;
    #pragma unroll
    for (int it = 0; it < 12; ++it) {
        const int h0 = it * 64 + sub * 4;
        const float4 x  = *reinterpret_cast<const float4*>(hrow + h0);
        const float4 q0 = *reinterpret_cast<const float4*>(W + h0 * 3);
        const float4 q1 = *reinterpret_cast<const float4*>(W + h0 * 3 + 4);
        const float4 q2 = *reinterpret_cast<const float4*>(W + h0 * 3 + 8);
        a0 = fmaf(x.x, q0.x, a0); a1 = fmaf(x.x, q0.y, a1); a2 = fmaf(x.x, q0.z, a2);
        a0 = fmaf(x.y, q0.w, a0); a1 = fmaf(x.y, q1.x, a1); a2 = fmaf(x.y, q1.y, a2);
        a0 = fmaf(x.z, q1.z, a0); a1 = fmaf(x.z, q1.w, a1); a2 = fmaf(x.z, q2.x, a2);
        a0 = fmaf(x.w, q2.y, a0); a1 = fmaf(x.w, q2.z, a1); a2 = fmaf(x.w, q2.w, a2);
    }
    #pragma unroll
    for (int d = 8; d; d >>= 1) {
        a0 += __shfl_xor(a0, d);
        a1 += __shfl_xor(a1, d);
        a2 += __shfl_xor(a2, d);
    }

    const float e0 = fmaxf(a0 + bias[0], 0.f);
    const float e1 = fmaxf(a1 + bias[1], 0.f);
    const float e2 = fmaxf(a2 + bias[2], 0.f);

    if (sub < 3) out[row * NT + sub] = (sub == 0) ? e0 : (sub == 1) ? e1 : e2;

    // ---- numerator term ----
    float term = 0.f;
    if (sub == 0) {
        const float esel = (labc == 0) ? e0 : (labc == 1) ? e1 : e2;
        if (p == 0) {
            term = startv[labc] + esel;               // boundary term
        } else if (mk) {
            term = trans[labp * 3 + labc] + esel;     // step term
        }
    }

    // ---- compose the wave's 4 step matrices (9 active lanes) ----
    const int il = (lane < 9) ? (lane / 3) : 0;
    const int jl = (lane < 9) ? (lane % 3) : 0;
    const float tc0 = trans[jl], tc1 = trans[3 + jl], tc2 = trans[6 + jl];
    float Pv = (il == jl) ? 0.f : NEGINF;

    const int pbase = p & ~3;
    #pragma unroll
    for (int k = 0; k < 4; ++k) {
        const int src = k << 4;
        const float ee0 = __shfl(e0, src);
        const float ee1 = __shfl(e1, src);
        const float ee2 = __shfl(e2, src);
        const int   mm  = __shfl(mk, src);
        const float Pi0 = __shfl(Pv, il * 3 + 0);
        const float Pi1 = __shfl(Pv, il * 3 + 1);
        const float Pi2 = __shfl(Pv, il * 3 + 2);
        const float ej  = (jl == 0) ? ee0 : (jl == 1) ? ee1 : ee2;
        const float q   = lse3(Pi0 + tc0, Pi1 + tc1, Pi2 + tc2) + ej;
        const bool act  = ((pbase + k) >= 1) && (mm != 0);
        Pv = act ? q : Pv;
    }

    const float np = __shfl(term, 0) + __shfl(term, 16) +
                     __shfl(term, 32) + __shfl(term, 48);

    if (lane < 9)  sP[wv][lane] = Pv;
    if (lane == 0) sP[wv][9]    = np;
    __syncthreads();
    if (wv != 0) return;

    // ---- fold 8 wave partials -> 1 block partial (wave 0) ----
    float Pb = (lane < 9) ? sP[0][lane] : 0.f;
    #pragma unroll
    for (int k = 1; k < 8; ++k) {
        const float Pi0 = __shfl(Pb, il * 3 + 0);
        const float Pi1 = __shfl(Pb, il * 3 + 1);
        const float Pi2 = __shfl(Pb, il * 3 + 2);
        const float q = lse3(Pi0 + sP[k][jl],
                             Pi1 + sP[k][3 + jl],
                             Pi2 + sP[k][6 + jl]);
        Pb = (lane < 9) ? q : Pb;
    }
    float* wp = ws + blockIdx.x * PSTRIDE;
    if (lane < 9)  wp[lane] = Pb;
    if (lane == 0) wp[9] = sP[0][9] + sP[1][9] + sP[2][9] + sP[3][9] +
                           sP[4][9] + sP[5][9] + sP[6][9] + sP[7][9];
}

// ---------------------------------------------------------------------------
// Kernel 2: combiner. One 64-lane block per batch: 16 block-partials on lanes
// 0..15 (loads issued first), 4-step ordered shfl_down tree, boundary terms,
// one atomicAdd per batch.
// ---------------------------------------------------------------------------
__global__ __launch_bounds__(64) void crf_combine(
    const float* __restrict__ emis,     // [NB*NS, NT] (= d_out)
    const int*   __restrict__ labels,   // [NB, NS]
    const int*   __restrict__ mask,     // [NB, NS]
    const float* __restrict__ startv,   // [NT]
    const float* __restrict__ endv,     // [NT]
    const float* __restrict__ ws,       // block partials
    float* __restrict__ nll)            // &d_out[EMIS_N]
{
    const int b    = blockIdx.x;
    const int lane = threadIdx.x;

    // issue partial loads first (independent of everything below)
    float P[9] = {0.f, NEGINF, NEGINF, NEGINF, 0.f, NEGINF, NEGINF, NEGINF, 0.f};
    float np = 0.f;
    if (lane < BPB) {
        const float* pa = ws + ((size_t)b * BPB + lane) * PSTRIDE;
        #pragma unroll
        for (int i = 0; i < 9; ++i) P[i] = pa[i];
        np = pa[9];
    }

    const int* mrow = mask   + b * NS;
    const int* lrow = labels + b * NS;
    int lsum = 0;
    #pragma unroll
    for (int k = 0; k < 8; ++k) lsum += mrow[lane + k * 64];
    #pragma unroll
    for (int d = 32; d; d >>= 1) lsum += __shfl_xor(lsum, d);
    const int len = lsum;

    // ordered tree over 16 partials
    #pragma unroll
    for (int d = 1; d < BPB; d <<= 1) {
        float Q[9];
        #pragma unroll
        for (int i = 0; i < 9; ++i) Q[i] = __shfl_down(P[i], d);
        const bool valid = (lane + d) < BPB;
        float R[9];
        #pragma unroll
        for (int i = 0; i < 3; ++i)
            #pragma unroll
            for (int j = 0; j < 3; ++j)
                R[i * 3 + j] = lse3(P[i * 3 + 0] + Q[0 + j],
                                    P[i * 3 + 1] + Q[3 + j],
                                    P[i * 3 + 2] + Q[6 + j]);
        #pragma unroll
        for (int i = 0; i < 9; ++i) P[i] = valid ? R[i] : P[i];
    }

    #pragma unroll
    for (int d = 32; d; d >>= 1) np += __shfl_xor(np, d);

    if (lane == 0) {
        const float* erow = emis + (size_t)b * NS * NT;
        const float a0 = startv[0] + erow[0];
        const float a1 = startv[1] + erow[1];
        const float a2 = startv[2] + erow[2];
        const float f0 = lse3(a0 + P[0], a1 + P[3], a2 + P[6]);
        const float f1 = lse3(a0 + P[1], a1 + P[4], a2 + P[7]);
        const float f2 = lse3(a0 + P[2], a1 + P[5], a2 + P[8]);
        const float logZ = lse3(f0 + endv[0], f1 + endv[1], f2 + endv[2]);

        const int tl = lrow[len - 1];
        const float num = np + endv[tl];   // start + e0 term already in np
        atomicAdd(nll, logZ - num);
    }
}

extern "C" void kernel_launch(void* const* d_in, const int* in_sizes, int n_in,
                              void* d_out, int out_size, void* d_ws, size_t ws_size,
                              hipStream_t stream) {
    const float* hidden = (const float*)d_in[0];
    const int*   labels = (const int*)  d_in[1];
    const int*   maskp  = (const int*)  d_in[2];
    const float* W      = (const float*)d_in[3];
    const float* bias   = (const float*)d_in[4];
    const float* trans  = (const float*)d_in[5];
    const float* startv = (const float*)d_in[6];
    const float* endv   = (const float*)d_in[7];
    float* out = (float*)d_out;
    float* ws  = (float*)d_ws;   // needs 1024 * 12 * 4 B = 48 KB

    emis_crf_kernel<<<NBLK, 512, 0, stream>>>(hidden, labels, maskp, W, bias,
                                              trans, startv, out, ws);
    crf_combine<<<NB, 64, 0, stream>>>(out, labels, maskp, startv, endv, ws,
                                       out + EMIS_N);
}